// Round 1
// baseline (482.660 us; speedup 1.0000x reference)
//
#include <hip/hip_runtime.h>
#include <cstdint>
#include <cstddef>

#define B_ROWS 8192
#define OUT_N  1024
#define EXC_IN 4096
#define INH_IN 2048
#define K_EXC  32
#define K_INH  16
#define TILE_N 4
#define MAIN_THREADS 512

// ---------------------------------------------------------------------------
// Top-K: one wave per row, register-resident keys, shuffle-only reduction.
// Key = (monotone_u32(float) << 12) | (4095 - idx)  -> tie = lowest idx wins.
// (unchanged from previous round — measured small vs main kernel)
// ---------------------------------------------------------------------------
template<int COLS, int K>
__device__ __forceinline__ void topk_row(const float* __restrict__ src,
                                         float2* __restrict__ orow, int lane)
{
    constexpr int E4 = COLS / 256;          // float4 iters per lane
    unsigned long long keys[E4 * 4];
#pragma unroll
    for (int i = 0; i < E4; ++i) {
        const float4 v = ((const float4*)src)[i * 64 + lane];
        const float vv[4] = {v.x, v.y, v.z, v.w};
#pragma unroll
        for (int q = 0; q < 4; ++q) {
            const int idx = (i * 64 + lane) * 4 + q;
            const unsigned int u = __float_as_uint(vv[q]);
            const unsigned int m = (u >> 31) ? ~u : (u | 0x80000000u);
            keys[i * 4 + q] = ((unsigned long long)m << 12)
                            | (unsigned long long)(4095 - idx);
        }
    }

    unsigned long long win = 0xFFFFFFFFFFFFFFFFull;   // matches nothing
#pragma unroll 1
    for (int r = 0; r < K; ++r) {
        unsigned long long best = 0ull;
#pragma unroll
        for (int i = 0; i < E4 * 4; ++i) {
            const unsigned long long k2 = (keys[i] == win) ? 0ull : keys[i];
            keys[i] = k2;
            best = (k2 > best) ? k2 : best;
        }
#pragma unroll
        for (int m = 1; m < 64; m <<= 1) {
            const unsigned long long o = __shfl_xor(best, m, 64);
            best = (o > best) ? o : best;
        }
        win = best;
        if (lane == 0) {
            const unsigned int idx = 4095u - (unsigned int)(win & 0xFFFull);
            const unsigned int mm  = (unsigned int)(win >> 12);
            const unsigned int u   = (mm & 0x80000000u) ? (mm & 0x7FFFFFFFu) : ~mm;
            const float v = __uint_as_float(u);
            orow[r] = make_float2(expf(v), __uint_as_float(idx));
        }
    }
}

__global__ __launch_bounds__(256, 1) void topk_both_kernel(
    const float* __restrict__ pwe, const float* __restrict__ pwi,
    float2* __restrict__ wexc, float2* __restrict__ winh)
{
    const int wid  = (blockIdx.x * 256 + threadIdx.x) >> 6;   // global wave id
    const int lane = threadIdx.x & 63;
    if (wid < OUT_N) {
        topk_row<EXC_IN, K_EXC>(pwe + (size_t)wid * EXC_IN,
                                wexc + (size_t)wid * K_EXC, lane);
    } else {
        const int r = wid - OUT_N;                            // 0..1023
        topk_row<INH_IN, K_INH>(pwi + (size_t)r * INH_IN,
                                winh + (size_t)r * K_INH, lane);
    }
}

// ---------------------------------------------------------------------------
// Main fused kernel, round-1 changes:
//  * 512 threads/block (same 64 KB LDS => still 2 blocks/CU, but 16 waves/CU
//    = 4 waves/SIMD instead of 2 -> 2x latency hiding). launch_bounds(512,4)
//    caps VGPR at 128 so registers don't become the occupancy limit.
//  * Staging via __builtin_amdgcn_global_load_lds size=4 with PER-LANE
//    (pre-swizzled) global source + LINEAR per-wave LDS dest: lane reads
//    x[n0+(lane&3)][chunk*16+(lane>>2)], HW writes LDS base+4*lane. This
//    reproduces the transposed [c][n] layout with ZERO transpose VALU and no
//    VGPR round-trip (deletes the xpose4 shuffle chains).
//  * Branch float4s prefetched into registers alongside x staging; their HBM
//    latency hides under both gather phases. (+32 VGPR, fits <=128 budget.)
// Gather stays: one ds_read_b128 per k covers 4 batch rows; weight rows read
// as float4 (2 k per load).
// ---------------------------------------------------------------------------
typedef __attribute__((address_space(1))) const unsigned int gu32_t;
typedef __attribute__((address_space(3))) unsigned int lu32_t;

__global__ __launch_bounds__(MAIN_THREADS, 4) void dendritic_main_kernel(
    const float*  __restrict__ x,
    const float*  __restrict__ inh,
    const float4* __restrict__ branch,   // [B][1024] float4
    const float2* __restrict__ wexc,     // [1024][32] (val, idx-bits)
    const float2* __restrict__ winh,     // [1024][16]
    const float4* __restrict__ wblock,   // [1024]
    const float*  __restrict__ presig,   // [1024]
    const float*  __restrict__ logalpha, // [1024]
    float*        __restrict__ out)      // [B][1024]
{
    __shared__ float sx[EXC_IN * TILE_N];   // 64 KB, [c][n] n-fast

    const int tid  = threadIdx.x;
    const int lane = tid & 63;
    const int wv   = tid >> 6;              // wave id 0..7
    const int n0   = blockIdx.x * TILE_N;

    // ---- stage x tile transposed: global_load_lds, 4B scatter-source ----
    // LDS float index f = chunk*64 + lane; column c = f>>2, row n = f&3.
    // Since chunk*64 is a multiple of 64: n = lane&3, c = chunk*16 + (lane>>2).
    const float* xsrc = x + (size_t)(n0 + (lane & 3)) * EXC_IN + (lane >> 2);
#pragma unroll
    for (int it = 0; it < 32; ++it) {
        const int chunk = it * 8 + wv;      // 0..255, 16 columns each
        __builtin_amdgcn_global_load_lds(
            (gu32_t*)(xsrc + chunk * 16),
            (lu32_t*)(sx + chunk * 64), 4, 0, 0);
    }

    // ---- prefetch branch rows (independent HBM loads, consumed in epilogue)
    float4 br[2][TILE_N];
#pragma unroll
    for (int j = 0; j < 2; ++j) {
        const int o = tid + j * MAIN_THREADS;
#pragma unroll
        for (int n = 0; n < TILE_N; ++n)
            br[j][n] = branch[(size_t)(n0 + n) * OUT_N + o];
    }

    __syncthreads();   // drains vmcnt(0) -> global_load_lds data visible

    // ---- excitation gather (b128) ----
    float acc_e[2][TILE_N];
#pragma unroll
    for (int j = 0; j < 2; ++j)
#pragma unroll
        for (int n = 0; n < TILE_N; ++n) acc_e[j][n] = 0.f;

#pragma unroll
    for (int j = 0; j < 2; ++j) {
        const int o = tid + j * MAIN_THREADS;
        const float4* wr = (const float4*)(wexc + (size_t)o * K_EXC);
#pragma unroll 8
        for (int k = 0; k < K_EXC / 2; ++k) {
            const float4 wv2 = wr[k];                 // {w0, idx0, w1, idx1}
            const int c0 = (int)__float_as_uint(wv2.y);
            const int c1 = (int)__float_as_uint(wv2.w);
            const float4 x0 = ((const float4*)sx)[c0];
            const float4 x1 = ((const float4*)sx)[c1];
            acc_e[j][0] = fmaf(x0.x, wv2.x, acc_e[j][0]);
            acc_e[j][1] = fmaf(x0.y, wv2.x, acc_e[j][1]);
            acc_e[j][2] = fmaf(x0.z, wv2.x, acc_e[j][2]);
            acc_e[j][3] = fmaf(x0.w, wv2.x, acc_e[j][3]);
            acc_e[j][0] = fmaf(x1.x, wv2.z, acc_e[j][0]);
            acc_e[j][1] = fmaf(x1.y, wv2.z, acc_e[j][1]);
            acc_e[j][2] = fmaf(x1.z, wv2.z, acc_e[j][2]);
            acc_e[j][3] = fmaf(x1.w, wv2.z, acc_e[j][3]);
        }
    }
    __syncthreads();   // all waves done reading sx before overwrite

    // ---- stage inh tile transposed (same scatter-source pattern) ----
    const float* isrc = inh + (size_t)(n0 + (lane & 3)) * INH_IN + (lane >> 2);
#pragma unroll
    for (int it = 0; it < 16; ++it) {
        const int chunk = it * 8 + wv;      // 0..127
        __builtin_amdgcn_global_load_lds(
            (gu32_t*)(isrc + chunk * 16),
            (lu32_t*)(sx + chunk * 64), 4, 0, 0);
    }
    __syncthreads();

    // ---- inhibition gather (b128) ----
    float acc_i[2][TILE_N];
#pragma unroll
    for (int j = 0; j < 2; ++j)
#pragma unroll
        for (int n = 0; n < TILE_N; ++n) acc_i[j][n] = 0.f;

#pragma unroll
    for (int j = 0; j < 2; ++j) {
        const int o = tid + j * MAIN_THREADS;
        const float4* wr = (const float4*)(winh + (size_t)o * K_INH);
#pragma unroll 8
        for (int k = 0; k < K_INH / 2; ++k) {
            const float4 wv2 = wr[k];
            const int c0 = (int)__float_as_uint(wv2.y);
            const int c1 = (int)__float_as_uint(wv2.w);
            const float4 x0 = ((const float4*)sx)[c0];
            const float4 x1 = ((const float4*)sx)[c1];
            acc_i[j][0] = fmaf(x0.x, wv2.x, acc_i[j][0]);
            acc_i[j][1] = fmaf(x0.y, wv2.x, acc_i[j][1]);
            acc_i[j][2] = fmaf(x0.z, wv2.x, acc_i[j][2]);
            acc_i[j][3] = fmaf(x0.w, wv2.x, acc_i[j][3]);
            acc_i[j][0] = fmaf(x1.x, wv2.z, acc_i[j][0]);
            acc_i[j][1] = fmaf(x1.y, wv2.z, acc_i[j][1]);
            acc_i[j][2] = fmaf(x1.z, wv2.z, acc_i[j][2]);
            acc_i[j][3] = fmaf(x1.w, wv2.z, acc_i[j][3]);
        }
    }

    // ---- branch contraction + voltage + reactivation ----
#pragma unroll
    for (int j = 0; j < 2; ++j) {
        const int o = tid + j * MAIN_THREADS;
        const float4 wb = wblock[o];
        const float cond  = wb.x + wb.y + wb.z + wb.w;
        const float Vth   = 1.f / (1.f + expf(-presig[o]));
        const float alpha = expf(logalpha[o]);
#pragma unroll
        for (int n = 0; n < TILE_N; ++n) {
            const float4 b4 = br[j][n];
            const float cur = b4.x * wb.x + b4.y * wb.y + b4.z * wb.z + b4.w * wb.w;
            const float e  = acc_e[j][n];
            const float ii = acc_i[j][n];
            const float num = e + cur;
            const float den = e + 1.f + cond + ii;
            const float v   = num / den;
            const float d   = v - Vth;
            const float r   = alpha * d * d;
            out[(size_t)(n0 + n) * OUT_N + o] = (d < 0.f) ? 0.f : r;
        }
    }
}

// ---------------------------------------------------------------------------
extern "C" void kernel_launch(void* const* d_in, const int* in_sizes, int n_in,
                              void* d_out, int out_size, void* d_ws, size_t ws_size,
                              hipStream_t stream)
{
    const float* x      = (const float*)d_in[0];
    const float* inh    = (const float*)d_in[1];
    const float* branch = (const float*)d_in[2];
    const float* pwe    = (const float*)d_in[3];
    const float* pwi    = (const float*)d_in[4];
    const float* wb     = (const float*)d_in[5];
    const float* ps     = (const float*)d_in[6];
    const float* la     = (const float*)d_in[7];
    float* out = (float*)d_out;

    float2* wexc = (float2*)d_ws;
    float2* winh = (float2*)((char*)d_ws + (size_t)OUT_N * K_EXC * sizeof(float2));

    // 1024 exc waves + 1024 inh waves, 4 waves/block -> 512 blocks
    topk_both_kernel<<<(2 * OUT_N) / 4, 256, 0, stream>>>(pwe, pwi, wexc, winh);

    dendritic_main_kernel<<<B_ROWS / TILE_N, MAIN_THREADS, 0, stream>>>(
        x, inh, (const float4*)branch, wexc, winh,
        (const float4*)wb, ps, la, out);
}

// Round 2
// 465.743 us; speedup vs baseline: 1.0363x; 1.0363x over previous
//
#include <hip/hip_runtime.h>
#include <cstdint>
#include <cstddef>

#define B_ROWS 8192
#define OUT_N  1024
#define EXC_IN 4096
#define INH_IN 2048
#define K_EXC  32
#define K_INH  16

#define TILE_N       2
#define MAIN_THREADS 1024
#define NBLK         512
#define NT_PER_BLK   (B_ROWS / TILE_N / NBLK)          // 8 tiles per block
#define COMB_FLOATS  ((EXC_IN + INH_IN) * TILE_N)      // 12288 floats = 48 KB
#define CHUNKS       (COMB_FLOATS / 64)                // 192 wave-instrs per tile
#define CHUNKS_PER_WAVE (CHUNKS / (MAIN_THREADS / 64)) // 12 per wave
#define XCHUNKS      (EXC_IN * TILE_N / 64)            // 128 chunks are x, rest inh

// ---------------------------------------------------------------------------
// Top-K: one wave per row, register-resident keys, shuffle-only reduction.
// Key = (monotone_u32(float) << 12) | (4095 - idx)  -> tie = lowest idx wins.
// CHANGE vs r1: output is written TRANSPOSED, wT[k][o], so the main kernel's
// weight loads are coalesced (64 lanes -> 64 consecutive float2s) instead of
// 16B-at-256B-stride (which amplified every weight load into 64 cache-line
// requests -- the dominant hidden cost in r0/r1).
// ---------------------------------------------------------------------------
template<int COLS, int K>
__device__ __forceinline__ void topk_row(const float* __restrict__ src,
                                         float2* __restrict__ ocol, int lane)
{
    constexpr int E4 = COLS / 256;          // float4 iters per lane
    unsigned long long keys[E4 * 4];
#pragma unroll
    for (int i = 0; i < E4; ++i) {
        const float4 v = ((const float4*)src)[i * 64 + lane];
        const float vv[4] = {v.x, v.y, v.z, v.w};
#pragma unroll
        for (int q = 0; q < 4; ++q) {
            const int idx = (i * 64 + lane) * 4 + q;
            const unsigned int u = __float_as_uint(vv[q]);
            const unsigned int m = (u >> 31) ? ~u : (u | 0x80000000u);
            keys[i * 4 + q] = ((unsigned long long)m << 12)
                            | (unsigned long long)(4095 - idx);
        }
    }

    unsigned long long win = 0xFFFFFFFFFFFFFFFFull;   // matches nothing
#pragma unroll 1
    for (int r = 0; r < K; ++r) {
        unsigned long long best = 0ull;
#pragma unroll
        for (int i = 0; i < E4 * 4; ++i) {
            const unsigned long long k2 = (keys[i] == win) ? 0ull : keys[i];
            keys[i] = k2;
            best = (k2 > best) ? k2 : best;
        }
#pragma unroll
        for (int m = 1; m < 64; m <<= 1) {
            const unsigned long long o = __shfl_xor(best, m, 64);
            best = (o > best) ? o : best;
        }
        win = best;
        if (lane == 0) {
            const unsigned int idx = 4095u - (unsigned int)(win & 0xFFFull);
            const unsigned int mm  = (unsigned int)(win >> 12);
            const unsigned int u   = (mm & 0x80000000u) ? (mm & 0x7FFFFFFFu) : ~mm;
            const float v = __uint_as_float(u);
            ocol[(size_t)r * OUT_N] = make_float2(expf(v), __uint_as_float(idx));
        }
    }
}

__global__ __launch_bounds__(256, 1) void topk_both_kernel(
    const float* __restrict__ pwe, const float* __restrict__ pwi,
    float2* __restrict__ wexcT, float2* __restrict__ winhT)
{
    const int wid  = (blockIdx.x * 256 + threadIdx.x) >> 6;   // global wave id
    const int lane = threadIdx.x & 63;
    if (wid < OUT_N) {
        topk_row<EXC_IN, K_EXC>(pwe + (size_t)wid * EXC_IN, wexcT + wid, lane);
    } else {
        const int r = wid - OUT_N;                            // 0..1023
        topk_row<INH_IN, K_INH>(pwi + (size_t)r * INH_IN, winhT + r, lane);
    }
}

// ---------------------------------------------------------------------------
// Main kernel, round-2: persistent double-buffered pipeline.
//  * 1024 threads, one output neuron o per thread for the whole kernel; per-o
//    constants (wblock/cond/Vth/alpha) hoisted out of the batch loop.
//  * TILE_N=2 batch rows per tile; x+inh staged together: 48 KB per buffer,
//    2 buffers = 96 KB LDS -> 1 block/CU, 16 waves.
//  * Staging via 4B global_load_lds with per-lane swizzled source
//    (row = lane&1, col = chunk*32 + (lane>>1)) -> transposed [c][n] layout
//    with linear LDS dest; source runs are 128B-contiguous per row.
//  * Raw s_barrier + counted s_waitcnt vmcnt(14): tile t+1's 12 staging loads
//    (+2 branch loads) stay IN FLIGHT across the barrier while tile t is
//    gathered -- no vmcnt(0) drain in the main loop (T3+T4 pattern).
//  * Weight loads now coalesced via transposed tables.
// Race check: iter t stages buf[(t+1)&1] (disjoint from buf[t&1] being read);
// buf[t&1] is overwritten first at iter t+1's stage issue, which is after the
// end-of-iter-t barrier -> all reads complete. All barriers wave-uniform.
// ---------------------------------------------------------------------------
typedef __attribute__((address_space(1))) const unsigned int gu32_t;
typedef __attribute__((address_space(3))) unsigned int lu32_t;

__global__ __launch_bounds__(MAIN_THREADS, 4) void dendritic_main_kernel(
    const float*  __restrict__ x,
    const float*  __restrict__ inh,
    const float4* __restrict__ branch,   // [B][1024] float4
    const float2* __restrict__ wexcT,    // [32][1024] (val, idx-bits)
    const float2* __restrict__ winhT,    // [16][1024]
    const float4* __restrict__ wblock,   // [1024]
    const float*  __restrict__ presig,   // [1024]
    const float*  __restrict__ logalpha, // [1024]
    float*        __restrict__ out)      // [B][1024]
{
    __shared__ float sx[2][COMB_FLOATS];   // 96 KB

    const int tid  = threadIdx.x;
    const int lane = tid & 63;
    const int w    = tid >> 6;             // wave 0..15
    const int o    = tid;                  // one output neuron per thread

    // ---- per-o constants, loaded once ----
    const float4 wb   = wblock[o];
    const float cond  = wb.x + wb.y + wb.z + wb.w;
    const float Vth   = 1.f / (1.f + expf(-presig[o]));
    const float alpha = expf(logalpha[o]);

    const int tile0 = blockIdx.x * NT_PER_BLK;
    const int srow  = lane & 1;            // batch row within tile
    const int scol  = lane >> 1;           // column offset within 32-col run

    // ---- prologue: stage tile0 into buf 0 ----
    {
        const int n0 = tile0 * TILE_N;
        const float* xs = x   + (size_t)(n0 + srow) * EXC_IN + scol;
        const float* is = inh + (size_t)(n0 + srow) * INH_IN + scol;
#pragma unroll
        for (int i = 0; i < CHUNKS_PER_WAVE; ++i) {
            const int c = i * 16 + w;
            const float* src = (c < XCHUNKS) ? (xs + c * 32)
                                             : (is + (c - XCHUNKS) * 32);
            __builtin_amdgcn_global_load_lds((gu32_t*)src,
                                             (lu32_t*)(&sx[0][0] + c * 64),
                                             4, 0, 0);
        }
    }

#pragma unroll 1
    for (int t = 0; t < NT_PER_BLK; ++t) {
        const int n0 = (tile0 + t) * TILE_N;
        const float* buf = &sx[t & 1][0];

        // ---- issue next-tile staging (stays in flight across barrier) ----
        if (t + 1 < NT_PER_BLK) {
            const int n1 = n0 + TILE_N;
            const float* xs = x   + (size_t)(n1 + srow) * EXC_IN + scol;
            const float* is = inh + (size_t)(n1 + srow) * INH_IN + scol;
            float* dst = &sx[(t + 1) & 1][0];
#pragma unroll
            for (int i = 0; i < CHUNKS_PER_WAVE; ++i) {
                const int c = i * 16 + w;
                const float* src = (c < XCHUNKS) ? (xs + c * 32)
                                                 : (is + (c - XCHUNKS) * 32);
                __builtin_amdgcn_global_load_lds((gu32_t*)src,
                                                 (lu32_t*)(dst + c * 64),
                                                 4, 0, 0);
            }
        }

        // ---- branch prefetch for this tile (consumed in epilogue) ----
        const float4 br0 = branch[(size_t)(n0 + 0) * OUT_N + o];
        const float4 br1 = branch[(size_t)(n0 + 1) * OUT_N + o];

        // ---- wait for THIS tile's staging only; keep t+1's in flight ----
        // outstanding: stage_t(12) + stage_{t+1}(12) + branch(2) -> leave 14.
        if (t + 1 < NT_PER_BLK) {
            asm volatile("s_waitcnt vmcnt(14)" ::: "memory");
        } else {
            asm volatile("s_waitcnt vmcnt(2)" ::: "memory");
        }
        __builtin_amdgcn_s_barrier();      // all waves' stage_t complete

        // ---- excitation gather (coalesced weights, b64 LDS reads) ----
        float e0 = 0.f, e1 = 0.f;
#pragma unroll 8
        for (int k = 0; k < K_EXC; ++k) {
            const float2 wv = wexcT[k * OUT_N + o];
            const int c = (int)__float_as_uint(wv.y);
            const float2 xv = ((const float2*)buf)[c];
            e0 = fmaf(xv.x, wv.x, e0);
            e1 = fmaf(xv.y, wv.x, e1);
        }

        // ---- inhibition gather ----
        float i0 = 0.f, i1 = 0.f;
#pragma unroll 8
        for (int k = 0; k < K_INH; ++k) {
            const float2 wv = winhT[k * OUT_N + o];
            const int c = (int)__float_as_uint(wv.y);
            const float2 xv = ((const float2*)buf)[EXC_IN + c];
            i0 = fmaf(xv.x, wv.x, i0);
            i1 = fmaf(xv.y, wv.x, i1);
        }

        // ---- epilogue: branch contraction + voltage + reactivation ----
        {
            const float cur0 = br0.x * wb.x + br0.y * wb.y + br0.z * wb.z + br0.w * wb.w;
            const float cur1 = br1.x * wb.x + br1.y * wb.y + br1.z * wb.z + br1.w * wb.w;
            const float v0 = (e0 + cur0) / (e0 + 1.f + cond + i0);
            const float v1 = (e1 + cur1) / (e1 + 1.f + cond + i1);
            const float d0 = v0 - Vth;
            const float d1 = v1 - Vth;
            const float r0 = alpha * d0 * d0;
            const float r1 = alpha * d1 * d1;
            out[(size_t)(n0 + 0) * OUT_N + o] = (d0 < 0.f) ? 0.f : r0;
            out[(size_t)(n0 + 1) * OUT_N + o] = (d1 < 0.f) ? 0.f : r1;
        }

        __builtin_amdgcn_s_barrier();      // reads of buf[t&1] done before
                                           // iter t+1 overwrites it
    }
}

// ---------------------------------------------------------------------------
extern "C" void kernel_launch(void* const* d_in, const int* in_sizes, int n_in,
                              void* d_out, int out_size, void* d_ws, size_t ws_size,
                              hipStream_t stream)
{
    const float* x      = (const float*)d_in[0];
    const float* inh    = (const float*)d_in[1];
    const float* branch = (const float*)d_in[2];
    const float* pwe    = (const float*)d_in[3];
    const float* pwi    = (const float*)d_in[4];
    const float* wb     = (const float*)d_in[5];
    const float* ps     = (const float*)d_in[6];
    const float* la     = (const float*)d_in[7];
    float* out = (float*)d_out;

    float2* wexcT = (float2*)d_ws;
    float2* winhT = (float2*)((char*)d_ws + (size_t)OUT_N * K_EXC * sizeof(float2));

    // 1024 exc waves + 1024 inh waves, 4 waves/block -> 512 blocks
    topk_both_kernel<<<(2 * OUT_N) / 4, 256, 0, stream>>>(pwe, pwi, wexcT, winhT);

    dendritic_main_kernel<<<NBLK, MAIN_THREADS, 0, stream>>>(
        x, inh, (const float4*)branch, wexcT, winhT,
        (const float4*)wb, ps, la, out);
}